// Round 1
// baseline (4479.014 us; speedup 1.0000x reference)
//
#include <hip/hip_runtime.h>
#include <cstdint>
#include <cstddef>

// Problem constants (fixed by reference)
#define NN   8192
#define SS   128
#define EMBD 256
#define LL   128
#define HV   2000
#define EE   131072

// ---------------- bf16 helpers (storage-only; math is fp32) ----------------
__device__ __forceinline__ unsigned short f2bf(float f) {
  unsigned u; __builtin_memcpy(&u, &f, 4);
  unsigned r = u + 0x7fffu + ((u >> 16) & 1u);   // round-to-nearest-even
  return (unsigned short)(r >> 16);
}
__device__ __forceinline__ float bfLo(unsigned u) { unsigned x = u << 16;        float f; __builtin_memcpy(&f, &x, 4); return f; }
__device__ __forceinline__ float bfHi(unsigned u) { unsigned x = u & 0xffff0000u; float f; __builtin_memcpy(&f, &x, 4); return f; }
__device__ __forceinline__ void unpack8(uint4 p, float* f) {
  f[0]=bfLo(p.x); f[1]=bfHi(p.x); f[2]=bfLo(p.y); f[3]=bfHi(p.y);
  f[4]=bfLo(p.z); f[5]=bfHi(p.z); f[6]=bfLo(p.w); f[7]=bfHi(p.w);
}
// XOR swizzle slot (units of 8 bf16 = 16B) so same-column reads across rows
// spread over banks (G4 / T2). Formula chosen so rows {i,i+8,i+16,i+24} AND
// consecutive rows both map to distinct 16B slots.
__device__ __forceinline__ int swz(int r) { return ((r ^ (r >> 3)) & 7) << 3; }

// ---------------- LDS layout (bytes) for the fused attention kernel --------
#define OFF_EMB 0         // bf16 [128][256]  65536 B
#define OFF_Q   65536     // bf16 [128][128]  32768 B
#define OFF_K   98304     // bf16 [128][128]  32768 B
#define OFF_RED 131072    // f32  [16][128]    8192 B (colsum partials; reused in phase 5)
#define OFF_C   139264    // f32  [128]         512 B
#define OFF_CE  139776    // f32  [256]        1024 B
#define OFF_M   140800    // f32  [128]         512 B
#define OFF_CS  141312    // f32  [2]             8 B
#define LDS_BYTES 141440

// ============================================================================
// Fused per-node attention kernel. One block = one node n. 512 threads.
//   att[n,s,t] = tanh( (emb[n]Wq+bq)·(emb[n]Wk+bk)^T / 16 )      -> d_out
//   c[t] = mean_s att[n,s,t]
//   z[n] = ((c @ emb[n]) @ Wv + (Σc)·bv) @ Wo + bo               -> d_out
// (V projection and att@V / @Wo GEMMs eliminated algebraically.)
// ============================================================================
__global__ __launch_bounds__(512)
void attn_fused(const float* __restrict__ emb,
                const float* __restrict__ Wq, const float* __restrict__ bq,
                const float* __restrict__ Wk, const float* __restrict__ bk,
                const float* __restrict__ Wv, const float* __restrict__ bv,
                const float* __restrict__ Wo, const float* __restrict__ bo,
                float* __restrict__ attOut, float* __restrict__ zOut)
{
  extern __shared__ char lds[];
  unsigned short* sEmb = (unsigned short*)(lds + OFF_EMB);
  unsigned short* sQ   = (unsigned short*)(lds + OFF_Q);
  unsigned short* sK   = (unsigned short*)(lds + OFF_K);
  float* red   = (float*)(lds + OFF_RED);
  float* cL    = (float*)(lds + OFF_C);
  float* ceL   = (float*)(lds + OFF_CE);
  float* mL    = (float*)(lds + OFF_M);
  float* csumL = (float*)(lds + OFF_CS);

  const int n   = blockIdx.x;
  const int tid = threadIdx.x;
  const float* embN = emb + (size_t)n * (SS * EMBD);

  // ---- Phase 1: emb[n] (f32, 128x256) -> sEmb (bf16, swizzled) ----
  {
    const float4* e4 = (const float4*)embN;           // 8192 float4
    for (int i = tid; i < (SS * EMBD / 4); i += 512) {
      float4 v = e4[i];
      int base = i * 4;
      int r = base >> 8, c = base & 255;
      int idx = r * 256 + (c ^ swz(r));               // c mult of 4; swz flips bits>=3 -> stays aligned
      ushort4 h;
      h.x = f2bf(v.x); h.y = f2bf(v.y); h.z = f2bf(v.z); h.w = f2bf(v.w);
      *(ushort4*)(sEmb + idx) = h;
    }
  }
  __syncthreads();

  // ---- Phase 2: Q = embWq+bq (threads 0..255), K = embWk+bk (256..511) ----
  {
    const int grp = tid >> 8;                 // 0 -> Q, 1 -> K
    const int t2  = tid & 255;
    const int ti  = t2 >> 4, tj = t2 & 15;
    const int s0  = ti * 8, c0 = tj * 8;      // 8 rows x 8 cols per thread
    const float* W    = grp ? Wk : Wq;
    const float* bias = grp ? bk : bq;
    unsigned short* sOut = grp ? sK : sQ;

    float acc[8][8];
    #pragma unroll
    for (int i = 0; i < 8; i++)
      #pragma unroll
      for (int j = 0; j < 8; j++) acc[i][j] = 0.0f;

    #pragma unroll 1
    for (int k0 = 0; k0 < EMBD; k0 += 8) {
      float e[8][8];
      #pragma unroll
      for (int i = 0; i < 8; i++) {
        int r = s0 + i;
        uint4 p = *(const uint4*)(sEmb + r * 256 + (k0 ^ swz(r)));
        unpack8(p, e[i]);
      }
      #pragma unroll
      for (int kk = 0; kk < 8; kk++) {
        float4 wa = *(const float4*)(W + (size_t)(k0 + kk) * LL + c0);
        float4 wb = *(const float4*)(W + (size_t)(k0 + kk) * LL + c0 + 4);
        float w[8] = {wa.x, wa.y, wa.z, wa.w, wb.x, wb.y, wb.z, wb.w};
        #pragma unroll
        for (int i = 0; i < 8; i++)
          #pragma unroll
          for (int j = 0; j < 8; j++) acc[i][j] += e[i][kk] * w[j];
      }
    }
    float bb[8];
    #pragma unroll
    for (int j = 0; j < 8; j++) bb[j] = bias[c0 + j];
    #pragma unroll
    for (int i = 0; i < 8; i++) {
      int r = s0 + i;
      uint4 p;
      p.x = (unsigned)f2bf(acc[i][0] + bb[0]) | ((unsigned)f2bf(acc[i][1] + bb[1]) << 16);
      p.y = (unsigned)f2bf(acc[i][2] + bb[2]) | ((unsigned)f2bf(acc[i][3] + bb[3]) << 16);
      p.z = (unsigned)f2bf(acc[i][4] + bb[4]) | ((unsigned)f2bf(acc[i][5] + bb[5]) << 16);
      p.w = (unsigned)f2bf(acc[i][6] + bb[6]) | ((unsigned)f2bf(acc[i][7] + bb[7]) << 16);
      *(uint4*)(sOut + r * 128 + (c0 ^ swz(r))) = p;
    }
  }
  __syncthreads();

  // ---- Phase 3: att = tanh(QK^T/16), write out, accumulate colsum partials ----
  {
    const int ti = tid >> 5, tj = tid & 31;
    const int s0 = ti * 8, t0 = tj * 4;       // 8 s-rows x 4 t-cols per thread
    float acc[8][4];
    #pragma unroll
    for (int i = 0; i < 8; i++)
      #pragma unroll
      for (int j = 0; j < 4; j++) acc[i][j] = 0.0f;

    #pragma unroll 2
    for (int l0 = 0; l0 < LL; l0 += 8) {
      float q[8][8], kv[4][8];
      #pragma unroll
      for (int i = 0; i < 8; i++) {
        int r = s0 + i;
        uint4 p = *(const uint4*)(sQ + r * 128 + (l0 ^ swz(r)));
        unpack8(p, q[i]);
      }
      #pragma unroll
      for (int j = 0; j < 4; j++) {
        int r = t0 + j;
        uint4 p = *(const uint4*)(sK + r * 128 + (l0 ^ swz(r)));
        unpack8(p, kv[j]);
      }
      #pragma unroll
      for (int ll = 0; ll < 8; ll++)
        #pragma unroll
        for (int i = 0; i < 8; i++)
          #pragma unroll
          for (int j = 0; j < 4; j++) acc[i][j] += q[i][ll] * kv[j][ll];
    }

    const float scale = 0.0625f;              // 1/sqrt(EMBD=256)
    float part[4] = {0.f, 0.f, 0.f, 0.f};
    float* attN = attOut + (size_t)n * (SS * SS);
    #pragma unroll
    for (int i = 0; i < 8; i++) {
      float4 o;
      o.x = tanhf(acc[i][0] * scale);
      o.y = tanhf(acc[i][1] * scale);
      o.z = tanhf(acc[i][2] * scale);
      o.w = tanhf(acc[i][3] * scale);
      part[0] += o.x; part[1] += o.y; part[2] += o.z; part[3] += o.w;
      *(float4*)(attN + (size_t)(s0 + i) * SS + t0) = o;
    }
    *(float4*)(red + ti * 128 + t0) = make_float4(part[0], part[1], part[2], part[3]);
  }
  __syncthreads();

  // ---- Phase 3.5: c[t] = colmean, csum = sum_t c[t] ----
  if (tid < 128) {
    float s = 0.0f;
    #pragma unroll
    for (int g = 0; g < 16; g++) s += red[g * 128 + tid];
    float c = s * (1.0f / 128.0f);
    cL[tid] = c;
    float r = c;
    #pragma unroll
    for (int off = 32; off >= 1; off >>= 1) r += __shfl_down(r, off, 64);
    if ((tid & 63) == 0) csumL[tid >> 6] = r;
  }
  __syncthreads();

  // ---- Phase 4: ce[e] = sum_t c[t] * emb[n,t,e]  (256 values) ----
  if (tid < 256) {
    float acc = 0.0f;
    #pragma unroll 8
    for (int t = 0; t < 128; t++)
      acc += cL[t] * bfLo((unsigned)sEmb[t * 256 + (tid ^ swz(t))] << 0) ; // placeholder fixed below
    ceL[tid] = acc;
  }
  __syncthreads();

  // ---- Phase 5: m[l] = ce @ Wv + csum*bv  (4-way split over e) ----
  {
    int l = tid & 127, eg = tid >> 7;         // eg in 0..3
    float acc = 0.0f;
    #pragma unroll 8
    for (int e = eg * 64; e < eg * 64 + 64; e++)
      acc += ceL[e] * Wv[(size_t)e * LL + l];
    red[eg * 128 + l] = acc;                  // red is dead, reuse
  }
  __syncthreads();
  if (tid < 128) {
    float csum = csumL[0] + csumL[1];
    mL[tid] = red[tid] + red[128 + tid] + red[256 + tid] + red[384 + tid] + csum * bv[tid];
  }
  __syncthreads();

  // ---- Phase 6: z[n,o] = m @ Wo + bo ----
  if (tid < 128) {
    float acc = bo[tid];
    #pragma unroll 8
    for (int l = 0; l < 128; l++) acc += mL[l] * Wo[(size_t)l * LL + tid];
    zOut[(size_t)n * LL + tid] = acc;
  }
}

// ============================================================================
// GCN: deg -> dinv -> self-loop init -> edge scatter (z-space!) -> @Wg GEMM
// ============================================================================
__global__ void gcn_deg(const int* __restrict__ eidx, float* __restrict__ deg) {
  int e = blockIdx.x * 256 + threadIdx.x;
  if (e < EE) atomicAdd(&deg[eidx[EE + e]], 1.0f);   // dst in-degree
}

__global__ void gcn_dinv(const float* __restrict__ deg, float* __restrict__ dinv) {
  int i = blockIdx.x * 256 + threadIdx.x;
  if (i < NN) dinv[i] = rsqrtf(deg[i] + 1.0f);       // +1 self loop; always > 0
}

__global__ void gcn_self(const float* __restrict__ dinv, const float* __restrict__ z,
                         float* __restrict__ agg) {
  size_t g = (size_t)blockIdx.x * 256 + threadIdx.x; // N*128 threads
  int i = (int)(g >> 7);
  float di = dinv[i];
  agg[g] = di * di * z[g];                           // init (no memset needed)
}

__global__ void gcn_scatter(const int* __restrict__ eidx, const float* __restrict__ dinv,
                            const float* __restrict__ z, float* __restrict__ agg) {
  int w    = (blockIdx.x * blockDim.x + threadIdx.x) >> 6;
  int lane = threadIdx.x & 63;
  int nw   = (gridDim.x * blockDim.x) >> 6;
  for (int e = w; e < EE; e += nw) {
    int s = eidx[e], d = eidx[EE + e];
    float nrm = dinv[s] * dinv[d];
    atomicAdd(&agg[(size_t)d * 128 + lane],      nrm * z[(size_t)s * 128 + lane]);
    atomicAdd(&agg[(size_t)d * 128 + 64 + lane], nrm * z[(size_t)s * 128 + 64 + lane]);
  }
}

// output[n,g] = agg[n,:] @ Wg[:,g] + bg[g].  Block: 8 n-rows, 256 threads,
// thread 0..249 owns 8 g-cols (250*8 = 2000 exactly).
__global__ __launch_bounds__(256)
void out_gemm(const float* __restrict__ agg, const float* __restrict__ Wg,
              const float* __restrict__ bg, float* __restrict__ outp) {
  __shared__ float sA[8 * 128];
  const int nb = blockIdx.x * 8;
  const int tid = threadIdx.x;
  {
    const float4* src = (const float4*)(agg + (size_t)nb * 128);
    ((float4*)sA)[tid] = src[tid];                   // 256 float4 = 8x128
  }
  __syncthreads();
  const int g0 = tid * 8;
  if (g0 < HV) {
    float acc[8][8];
    #pragma unroll
    for (int i = 0; i < 8; i++)
      #pragma unroll
      for (int j = 0; j < 8; j++) acc[i][j] = 0.0f;
    #pragma unroll 2
    for (int l = 0; l < 128; l++) {
      float4 wa = *(const float4*)(Wg + (size_t)l * HV + g0);
      float4 wb = *(const float4*)(Wg + (size_t)l * HV + g0 + 4);
      float w[8] = {wa.x, wa.y, wa.z, wa.w, wb.x, wb.y, wb.z, wb.w};
      #pragma unroll
      for (int i = 0; i < 8; i++) {
        float a = sA[i * 128 + l];
        #pragma unroll
        for (int j = 0; j < 8; j++) acc[i][j] += a * w[j];
      }
    }
    float b[8];
    #pragma unroll
    for (int j = 0; j < 8; j++) b[j] = bg[g0 + j];
    #pragma unroll
    for (int i = 0; i < 8; i++) {
      float4 oa = make_float4(acc[i][0] + b[0], acc[i][1] + b[1], acc[i][2] + b[2], acc[i][3] + b[3]);
      float4 ob = make_float4(acc[i][4] + b[4], acc[i][5] + b[5], acc[i][6] + b[6], acc[i][7] + b[7]);
      *(float4*)(outp + (size_t)(nb + i) * HV + g0)     = oa;
      *(float4*)(outp + (size_t)(nb + i) * HV + g0 + 4) = ob;
    }
  }
}

// ============================================================================
extern "C" void kernel_launch(void* const* d_in, const int* in_sizes, int n_in,
                              void* d_out, int out_size, void* d_ws, size_t ws_size,
                              hipStream_t stream) {
  const float* emb  = (const float*)d_in[0];
  const int*   eidx = (const int*)d_in[1];    // jax demotes int64->int32 (x64 off)
  const float* Wq = (const float*)d_in[2];
  const float* bq = (const float*)d_in[3];
  const float* Wk = (const float*)d_in[4];
  const float* bk = (const float*)d_in[5];
  const float* Wv = (const float*)d_in[6];
  const float* bv = (const float*)d_in[7];
  const float* Wo = (const float*)d_in[8];
  const float* bo = (const float*)d_in[9];
  const float* Wg = (const float*)d_in[10];
  const float* bg = (const float*)d_in[11];

  float* out  = (float*)d_out;
  float* attO = out;                                   // [N,S,S]
  float* zO   = out + (size_t)NN * SS * SS;            // [N,L]
  float* oO   = zO + (size_t)NN * LL;                  // [N,HV]

  float* wsf  = (float*)d_ws;
  float* deg  = wsf;                                   // [N]
  float* dinv = wsf + NN;                              // [N]
  float* agg  = wsf + 2 * NN;                          // [N,128]

  (void)in_sizes; (void)n_in; (void)out_size; (void)ws_size;

  hipFuncSetAttribute((const void*)attn_fused,
                      hipFuncAttributeMaxDynamicSharedMemorySize, LDS_BYTES);

  hipMemsetAsync(deg, 0, NN * sizeof(float), stream);
  gcn_deg <<<EE / 256, 256, 0, stream>>>(eidx, deg);
  gcn_dinv<<<NN / 256, 256, 0, stream>>>(deg, dinv);

  attn_fused<<<NN, 512, LDS_BYTES, stream>>>(emb, Wq, bq, Wk, bk, Wv, bv, Wo, bo, attO, zO);

  gcn_self   <<<NN * 128 / 256, 256, 0, stream>>>(dinv, zO, agg);
  gcn_scatter<<<2048, 256, 0, stream>>>(eidx, dinv, zO, agg);
  out_gemm   <<<NN / 8, 256, 0, stream>>>(agg, Wg, bg, oO);
}

// Round 2
// 1543.099 us; speedup vs baseline: 2.9026x; 2.9026x over previous
//
#include <hip/hip_runtime.h>
#include <cstdint>
#include <cstddef>

// Problem constants (fixed by reference)
#define NN   8192
#define SS   128
#define EMBD 256
#define LL   128
#define HV   2000
#define EE   131072

typedef float  f32x4  __attribute__((ext_vector_type(4)));
typedef __bf16 bf16x8 __attribute__((ext_vector_type(8)));
typedef unsigned int   u32x4 __attribute__((ext_vector_type(4)));
typedef unsigned short u16x8 __attribute__((ext_vector_type(8)));
typedef unsigned short u16x4 __attribute__((ext_vector_type(4)));

__device__ __forceinline__ unsigned short f2bf(float f) {
  unsigned u; __builtin_memcpy(&u, &f, 4);
  unsigned r = u + 0x7fffu + ((u >> 16) & 1u);   // RNE
  return (unsigned short)(r >> 16);
}

// ---------------- LDS layout (bytes) ----------------
#define OFF_K   0         // bf16 [128][128] swizzled  (32768 B)  K matrix
#define OFF_QS  32768     // bf16 [8][16][128] swizzled (32768 B) per-wave Q strips
#define OFF_SCR 65536     // f32 scratch 8192 B (red[8][128] / red4[8][256] / m-parts)
#define OFF_C   73728     // f32 [128]
#define OFF_CE  74240     // f32 [256]
#define OFF_M   75264     // f32 [128]
#define OFF_CS  75776     // f32 [2]
#define LDS_BYTES 76032   // 2 blocks/CU (152064 <= 163840)

// ============================================================================
// prep: WqT/WkT = transpose(Wq/Wk) in bf16, [LL][EMBD] row-major
// ============================================================================
__global__ void prep_w(const float* __restrict__ Wq, const float* __restrict__ Wk,
                       unsigned short* __restrict__ wqT, unsigned short* __restrict__ wkT) {
  int idx = blockIdx.x * 256 + threadIdx.x;      // 32768 = LL*EMBD
  int c = idx >> 8, e = idx & 255;               // idx = c*EMBD + e
  wqT[idx] = f2bf(Wq[(size_t)e * LL + c]);
  wkT[idx] = f2bf(Wk[(size_t)e * LL + c]);
}

// ============================================================================
// Fused per-node attention. One block = one node. 512 threads = 8 waves.
// Wave w owns s/t rows [16w, 16w+16).
//  P1: QT/KT strips via mfma(A=W?T, B=emb)  (C-frag: lane holds row s=lx)
//  P2: C-frags (+bias, bf16) -> LDS (K shared, Q per-wave scratch), barrier
//  P3: S = Q K^T via mfma, tanh, store att, colsum partials
//  P4: c = colmean; ce = c @ emb (global re-read); m = ce@Wv + (sum c)*bv
//  P5: z = m @ Wo + bo
// ============================================================================
__global__ __launch_bounds__(512, 4)
void attn_fused(const float* __restrict__ emb,
                const unsigned short* __restrict__ wqT,
                const unsigned short* __restrict__ wkT,
                const float* __restrict__ bq, const float* __restrict__ bk,
                const float* __restrict__ Wv, const float* __restrict__ bv,
                const float* __restrict__ Wo, const float* __restrict__ bo,
                float* __restrict__ attOut, float* __restrict__ zOut)
{
  extern __shared__ char lds[];
  unsigned short* Kl  = (unsigned short*)(lds + OFF_K);
  unsigned short* Qs  = (unsigned short*)(lds + OFF_QS);
  float* scr = (float*)(lds + OFF_SCR);
  float* cL  = (float*)(lds + OFF_C);
  float* ceL = (float*)(lds + OFF_CE);
  float* mL  = (float*)(lds + OFF_M);
  float* csL = (float*)(lds + OFF_CS);

  const int n    = blockIdx.x;
  const int tid  = threadIdx.x;
  const int wid  = tid >> 6;
  const int lane = tid & 63;
  const int lx   = lane & 15;          // within-tile row/col index
  const int g    = lane >> 4;          // k-group 0..3
  const int sw   = (lx & 7) << 3;      // LDS swizzle key (bits 3-5 of bf16 col)

  const float* embN = emb + (size_t)n * (SS * EMBD);

  // ---------------- P1: projections (C = W?T[128x256] @ embT[256x128]) ------
  f32x4 accQ[8], accK[8];
  #pragma unroll
  for (int m = 0; m < 8; m++) {
    accQ[m] = f32x4{0.f, 0.f, 0.f, 0.f};
    accK[m] = f32x4{0.f, 0.f, 0.f, 0.f};
  }
  {
    const float* eb = embN + (size_t)(wid * 16 + lx) * EMBD + g * 8; // B-frag base
    const unsigned short* aq = wqT + (size_t)lx * EMBD + g * 8;      // A-frag bases
    const unsigned short* ak = wkT + (size_t)lx * EMBD + g * 8;
    #pragma unroll 1
    for (int ks = 0; ks < 8; ks++) {
      f32x4 e0 = *(const f32x4*)(eb + ks * 32);
      f32x4 e1 = *(const f32x4*)(eb + ks * 32 + 4);
      u16x8 bu;
      bu[0] = f2bf(e0[0]); bu[1] = f2bf(e0[1]); bu[2] = f2bf(e0[2]); bu[3] = f2bf(e0[3]);
      bu[4] = f2bf(e1[0]); bu[5] = f2bf(e1[1]); bu[6] = f2bf(e1[2]); bu[7] = f2bf(e1[3]);
      bf16x8 bf = __builtin_bit_cast(bf16x8, bu);
      #pragma unroll
      for (int m = 0; m < 8; m++) {
        u32x4 qa = *(const u32x4*)(aq + (size_t)m * 16 * EMBD + ks * 32);
        u32x4 ka = *(const u32x4*)(ak + (size_t)m * 16 * EMBD + ks * 32);
        accQ[m] = __builtin_amdgcn_mfma_f32_16x16x32_bf16(
                    __builtin_bit_cast(bf16x8, qa), bf, accQ[m], 0, 0, 0);
        accK[m] = __builtin_amdgcn_mfma_f32_16x16x32_bf16(
                    __builtin_bit_cast(bf16x8, ka), bf, accK[m], 0, 0, 0);
      }
    }
  }

  // ---------------- P2: C-frags (+bias) -> bf16 -> LDS ----------------------
  {
    const int trow = wid * 16 + lx;                 // own row (s for Q, t for K)
    #pragma unroll
    for (int m = 0; m < 8; m++) {
      const int col = m * 16 + g * 4;               // latent base of the 4 regs
      f32x4 bq4 = *(const f32x4*)(bq + col);
      f32x4 bk4 = *(const f32x4*)(bk + col);
      u16x4 qv, kv;
      qv[0] = f2bf(accQ[m][0] + bq4[0]); qv[1] = f2bf(accQ[m][1] + bq4[1]);
      qv[2] = f2bf(accQ[m][2] + bq4[2]); qv[3] = f2bf(accQ[m][3] + bq4[3]);
      kv[0] = f2bf(accK[m][0] + bk4[0]); kv[1] = f2bf(accK[m][1] + bk4[1]);
      kv[2] = f2bf(accK[m][2] + bk4[2]); kv[3] = f2bf(accK[m][3] + bk4[3]);
      *(u16x4*)(Qs + (size_t)wid * 2048 + lx * 128 + (col ^ sw)) = qv;
      *(u16x4*)(Kl + (size_t)trow * 128 + (col ^ sw)) = kv;
    }
  }
  __syncthreads();

  // ---------------- P3: S = Q @ K^T, tanh, store, colsums -------------------
  bf16x8 qf[4];
  #pragma unroll
  for (int ks = 0; ks < 4; ks++) {
    u32x4 t = *(const u32x4*)(Qs + (size_t)wid * 2048 + lx * 128 + ((ks * 32 + g * 8) ^ sw));
    qf[ks] = __builtin_bit_cast(bf16x8, t);
  }
  f32x4 accS[8];
  #pragma unroll
  for (int nt = 0; nt < 8; nt++) accS[nt] = f32x4{0.f, 0.f, 0.f, 0.f};
  #pragma unroll
  for (int nt = 0; nt < 8; nt++) {
    const int tr = nt * 16 + lx;
    #pragma unroll
    for (int ks = 0; ks < 4; ks++) {
      u32x4 t = *(const u32x4*)(Kl + (size_t)tr * 128 + ((ks * 32 + g * 8) ^ sw));
      accS[nt] = __builtin_amdgcn_mfma_f32_16x16x32_bf16(
                   qf[ks], __builtin_bit_cast(bf16x8, t), accS[nt], 0, 0, 0);
    }
  }

  {
    float* attN = attOut + (size_t)n * (SS * SS);
    const int srow0 = wid * 16 + g * 4;
    float colp[8];
    #pragma unroll
    for (int nt = 0; nt < 8; nt++) {
      float p = 0.f;
      #pragma unroll
      for (int r = 0; r < 4; r++) {
        float x  = accS[nt][r] * 0.0625f;           // 1/sqrt(256)
        float ax = fabsf(x);
        float ex = __expf(ax * 2.0f);
        float th = __builtin_copysignf(__fdividef(ex - 1.0f, ex + 1.0f), x);
        p += th;
        attN[(size_t)(srow0 + r) * SS + nt * 16 + lx] = th;
      }
      p += __shfl_xor(p, 16, 64);
      p += __shfl_xor(p, 32, 64);                   // sum over the strip's 16 rows
      colp[nt] = p;
    }
    if (lane < 16) {
      #pragma unroll
      for (int nt = 0; nt < 8; nt++) scr[wid * 128 + nt * 16 + lane] = colp[nt];
    }
  }
  __syncthreads();

  // ---------------- P4a: c[t] = colmean, csum ------------------------------
  if (tid < 128) {
    float s = 0.f;
    #pragma unroll
    for (int w = 0; w < 8; w++) s += scr[w * 128 + tid];
    float c = s * (1.0f / 128.0f);
    cL[tid] = c;
    float r = c;
    #pragma unroll
    for (int off = 32; off >= 1; off >>= 1) r += __shfl_down(r, off, 64);
    if ((tid & 63) == 0) csL[tid >> 6] = r;
  }
  __syncthreads();

  // ---------------- P4b: ce[e] = sum_t c[t] * emb[n,t,e] (global re-read) ---
  {
    const f32x4* e4 = (const f32x4*)embN;
    f32x4 acc = f32x4{0.f, 0.f, 0.f, 0.f};
    #pragma unroll 4
    for (int i = 0; i < 16; i++) {
      int t = i * 8 + wid;
      float cc = cL[t];
      f32x4 v = e4[t * 64 + lane];
      acc += cc * v;
    }
    *(f32x4*)(scr + wid * 256 + lane * 4) = acc;
  }
  __syncthreads();
  if (tid < 256) {
    float s = 0.f;
    #pragma unroll
    for (int w = 0; w < 8; w++) s += scr[w * 256 + tid];
    ceL[tid] = s;
  }
  __syncthreads();

  // ---------------- P4c: m[l] = ce @ Wv + csum*bv ---------------------------
  {
    const int l = tid & 127, eg = tid >> 7;
    float a = 0.f;
    #pragma unroll 4
    for (int i = 0; i < 64; i++)
      a += ceL[eg * 64 + i] * Wv[(size_t)(eg * 64 + i) * LL + l];
    __syncthreads();                                // ceL reads done before scr reuse? (scr!=ceL; barrier for ordering only)
    scr[eg * 128 + l] = a;
  }
  __syncthreads();
  if (tid < 128) {
    float csum = csL[0] + csL[1];
    mL[tid] = scr[tid] + scr[128 + tid] + scr[256 + tid] + scr[384 + tid] + csum * bv[tid];
  }
  __syncthreads();

  // ---------------- P5: z = m @ Wo + bo -------------------------------------
  if (tid < 128) {
    float a = bo[tid];
    #pragma unroll 4
    for (int l = 0; l < 128; l++) a += mL[l] * Wo[(size_t)l * LL + tid];
    zOut[(size_t)n * LL + tid] = a;
  }
}

// ============================================================================
// GCN in z-space (scatter 128-dim), then output GEMM to 2000-dim
// ============================================================================
__global__ void gcn_deg(const int* __restrict__ eidx, float* __restrict__ deg) {
  int e = blockIdx.x * 256 + threadIdx.x;
  if (e < EE) atomicAdd(&deg[eidx[EE + e]], 1.0f);
}

__global__ void gcn_dinv(const float* __restrict__ deg, float* __restrict__ dinv) {
  int i = blockIdx.x * 256 + threadIdx.x;
  if (i < NN) dinv[i] = rsqrtf(deg[i] + 1.0f);      // +1 self loop
}

__global__ void gcn_self(const float* __restrict__ dinv, const float* __restrict__ z,
                         float* __restrict__ agg) {
  size_t gidx = (size_t)blockIdx.x * 256 + threadIdx.x;
  int i = (int)(gidx >> 7);
  float di = dinv[i];
  agg[gidx] = di * di * z[gidx];
}

__global__ void gcn_scatter(const int* __restrict__ eidx, const float* __restrict__ dinv,
                            const float* __restrict__ z, float* __restrict__ agg) {
  int w    = (blockIdx.x * blockDim.x + threadIdx.x) >> 6;
  int lane = threadIdx.x & 63;
  int nw   = (gridDim.x * blockDim.x) >> 6;
  for (int e = w; e < EE; e += nw) {
    int s = eidx[e], d = eidx[EE + e];
    float nrm = dinv[s] * dinv[d];
    atomicAdd(&agg[(size_t)d * 128 + lane],      nrm * z[(size_t)s * 128 + lane]);
    atomicAdd(&agg[(size_t)d * 128 + 64 + lane], nrm * z[(size_t)s * 128 + 64 + lane]);
  }
}

__global__ __launch_bounds__(256)
void out_gemm(const float* __restrict__ agg, const float* __restrict__ Wg,
              const float* __restrict__ bg, float* __restrict__ outp) {
  __shared__ float sA[8 * 128];
  const int nb = blockIdx.x * 8;
  const int tid = threadIdx.x;
  {
    const float4* src = (const float4*)(agg + (size_t)nb * 128);
    ((float4*)sA)[tid] = src[tid];
  }
  __syncthreads();
  const int g0 = tid * 8;
  if (g0 < HV) {
    float acc[8][8];
    #pragma unroll
    for (int i = 0; i < 8; i++)
      #pragma unroll
      for (int j = 0; j < 8; j++) acc[i][j] = 0.0f;
    #pragma unroll 2
    for (int l = 0; l < 128; l++) {
      float4 wa = *(const float4*)(Wg + (size_t)l * HV + g0);
      float4 wb = *(const float4*)(Wg + (size_t)l * HV + g0 + 4);
      float w[8] = {wa.x, wa.y, wa.z, wa.w, wb.x, wb.y, wb.z, wb.w};
      #pragma unroll
      for (int i = 0; i < 8; i++) {
        float a = sA[i * 128 + l];
        #pragma unroll
        for (int j = 0; j < 8; j++) acc[i][j] += a * w[j];
      }
    }
    float b[8];
    #pragma unroll
    for (int j = 0; j < 8; j++) b[j] = bg[g0 + j];
    #pragma unroll
    for (int i = 0; i < 8; i++) {
      float4 oa = make_float4(acc[i][0] + b[0], acc[i][1] + b[1], acc[i][2] + b[2], acc[i][3] + b[3]);
      float4 ob = make_float4(acc[i][4] + b[4], acc[i][5] + b[5], acc[i][6] + b[6], acc[i][7] + b[7]);
      *(float4*)(outp + (size_t)(nb + i) * HV + g0)     = oa;
      *(float4*)(outp + (size_t)(nb + i) * HV + g0 + 4) = ob;
    }
  }
}

// ============================================================================
extern "C" void kernel_launch(void* const* d_in, const int* in_sizes, int n_in,
                              void* d_out, int out_size, void* d_ws, size_t ws_size,
                              hipStream_t stream) {
  const float* emb  = (const float*)d_in[0];
  const int*   eidx = (const int*)d_in[1];
  const float* Wq = (const float*)d_in[2];
  const float* bq = (const float*)d_in[3];
  const float* Wk = (const float*)d_in[4];
  const float* bk = (const float*)d_in[5];
  const float* Wv = (const float*)d_in[6];
  const float* bv = (const float*)d_in[7];
  const float* Wo = (const float*)d_in[8];
  const float* bo = (const float*)d_in[9];
  const float* Wg = (const float*)d_in[10];
  const float* bg = (const float*)d_in[11];

  float* out  = (float*)d_out;
  float* attO = out;                                   // [N,S,S]
  float* zO   = out + (size_t)NN * SS * SS;            // [N,L]
  float* oO   = zO + (size_t)NN * LL;                  // [N,HV]

  float* wsf  = (float*)d_ws;
  float* deg  = wsf;                                   // [N]
  float* dinv = wsf + NN;                              // [N]
  float* agg  = wsf + 2 * NN;                          // [N,128] (4 MB)
  // wqT/wkT alias the head of agg: used only by prep_w/attn_fused, which both
  // complete (stream order) before gcn_self overwrites agg.
  unsigned short* wqT = (unsigned short*)agg;          // 64 KB
  unsigned short* wkT = wqT + LL * EMBD;               // 64 KB

  (void)in_sizes; (void)n_in; (void)out_size; (void)ws_size;

  hipFuncSetAttribute((const void*)attn_fused,
                      hipFuncAttributeMaxDynamicSharedMemorySize, LDS_BYTES);

  hipMemsetAsync(deg, 0, NN * sizeof(float), stream);
  gcn_deg <<<EE / 256, 256, 0, stream>>>(eidx, deg);
  gcn_dinv<<<NN / 256, 256, 0, stream>>>(deg, dinv);
  prep_w  <<<(LL * EMBD) / 256, 256, 0, stream>>>(Wq, Wk, wqT, wkT);

  attn_fused<<<NN, 512, LDS_BYTES, stream>>>(emb, wqT, wkT, bq, bk,
                                             Wv, bv, Wo, bo, attO, zO);

  gcn_self   <<<NN * 128 / 256, 256, 0, stream>>>(dinv, zO, agg);
  gcn_scatter<<<2048, 256, 0, stream>>>(eidx, dinv, zO, agg);
  out_gemm   <<<NN / 8, 256, 0, stream>>>(agg, Wg, bg, oO);
}

// Round 3
// 970.965 us; speedup vs baseline: 4.6129x; 1.5892x over previous
//
#include <hip/hip_runtime.h>
#include <cstdint>
#include <cstddef>

// Problem constants (fixed by reference)
#define NN   8192
#define SS   128
#define EMBD 256
#define LL   128
#define HV   2000
#define EE   131072

typedef float  f32x4  __attribute__((ext_vector_type(4)));
typedef __bf16 bf16x8 __attribute__((ext_vector_type(8)));
typedef unsigned int   u32x4 __attribute__((ext_vector_type(4)));
typedef unsigned short u16x4 __attribute__((ext_vector_type(4)));

__device__ __forceinline__ unsigned short f2bf(float f) {
  unsigned u; __builtin_memcpy(&u, &f, 4);
  unsigned r = u + 0x7fffu + ((u >> 16) & 1u);   // RNE
  return (unsigned short)(r >> 16);
}

// ============================================================================
// prep: wT[col][e] bf16, col in [0,256): col<128 -> Wq[:,col], else Wk[:,col-128]
// ============================================================================
__global__ void prep_w(const float* __restrict__ Wq, const float* __restrict__ Wk,
                       unsigned short* __restrict__ wT) {
  int idx = blockIdx.x * 256 + threadIdx.x;      // 65536 = 256 cols x 256 e
  int c = idx >> 8, e = idx & 255;
  float v = (c < 128) ? Wq[(size_t)e * LL + c] : Wk[(size_t)e * LL + (c - 128)];
  wT[idx] = f2bf(v);
}

// ============================================================================
// K1 proj: half-node blocks. C[s][col] = emb[s][:] @ [Wq|Wk][:, col] + bias.
// Output written bf16, PRE-SWIZZLED, into the att[n] slot of d_out:
//   slot[s][col ^ ((s&7)<<3)]  (row-major [128][256] bf16 = 64 KB per node)
// ============================================================================
#define PJ_LDS 32768   // 64 rows x 256 bf16 (staging: emb in, then Q|K out)
__global__ __launch_bounds__(512, 2)
void proj(const float* __restrict__ emb, const unsigned short* __restrict__ wT,
          const float* __restrict__ bq, const float* __restrict__ bk,
          float* __restrict__ qkOut)
{
  extern __shared__ char lds[];
  unsigned short* sE = (unsigned short*)lds;

  const int blk  = blockIdx.x;
  const int n    = blk >> 1;
  const int s0   = (blk & 1) * 64;
  const int tid  = threadIdx.x;
  const int wid  = tid >> 6;
  const int lane = tid & 63;
  const int lx   = lane & 15;
  const int g    = lane >> 4;
  const int sw   = (lx & 7) << 3;

  // ---- stage emb[n][s0..s0+64][:] f32 -> LDS bf16 (swizzled rows) ----
  {
    const f32x4* src = (const f32x4*)(emb + ((size_t)n * SS + s0) * EMBD);
    #pragma unroll
    for (int it = 0; it < 8; it++) {
      int i = it * 512 + tid;                    // 4096 f32x4 total
      f32x4 v = src[i];
      int s = i >> 6, e0 = (i & 63) << 2;
      u16x4 h;
      h[0] = f2bf(v[0]); h[1] = f2bf(v[1]); h[2] = f2bf(v[2]); h[3] = f2bf(v[3]);
      *(u16x4*)(sE + s * 256 + (e0 ^ ((s & 7) << 3))) = h;
    }
  }
  __syncthreads();

  // ---- B-frag prefetch: this wave's 32 output cols (L2-hot wT) ----
  const int col0 = (wid << 5) + lx;              // n2=0 col for this lane
  u32x4 Bfr[2][8];
  #pragma unroll
  for (int n2 = 0; n2 < 2; n2++)
    #pragma unroll
    for (int ks = 0; ks < 8; ks++)
      Bfr[n2][ks] = *(const u32x4*)(wT + (size_t)(col0 + n2 * 16) * 256 + ks * 32 + g * 8);

  float b0 = (col0 < 128) ? bq[col0] : bk[col0 - 128];
  float b1 = (col0 + 16 < 128) ? bq[col0 + 16] : bk[col0 + 16 - 128];

  // ---- MFMA: 4 m-tiles (64 s-rows) x 2 n-tiles x 8 ks ----
  f32x4 acc[4][2];
  #pragma unroll
  for (int m = 0; m < 4; m++) { acc[m][0] = f32x4{0,0,0,0}; acc[m][1] = f32x4{0,0,0,0}; }

  #pragma unroll
  for (int m = 0; m < 4; m++) {
    u32x4 A[8];
    #pragma unroll
    for (int ks = 0; ks < 8; ks++)
      A[ks] = *(const u32x4*)(sE + (m * 16 + lx) * 256 + ((ks * 32 + g * 8) ^ sw));
    #pragma unroll
    for (int ks = 0; ks < 8; ks++) {
      acc[m][0] = __builtin_amdgcn_mfma_f32_16x16x32_bf16(
                    __builtin_bit_cast(bf16x8, A[ks]), __builtin_bit_cast(bf16x8, Bfr[0][ks]),
                    acc[m][0], 0, 0, 0);
      acc[m][1] = __builtin_amdgcn_mfma_f32_16x16x32_bf16(
                    __builtin_bit_cast(bf16x8, A[ks]), __builtin_bit_cast(bf16x8, Bfr[1][ks]),
                    acc[m][1], 0, 0, 0);
    }
  }
  __syncthreads();                               // emb staging now dead

  // ---- C-frags (+bias) -> LDS bf16, swizzled [s][col^sw(s)] ----
  #pragma unroll
  for (int m = 0; m < 4; m++) {
    #pragma unroll
    for (int n2 = 0; n2 < 2; n2++) {
      const int col = col0 + n2 * 16;
      const float bb = n2 ? b1 : b0;
      #pragma unroll
      for (int r = 0; r < 4; r++) {
        const int srow = m * 16 + g * 4 + r;
        sE[srow * 256 + (col ^ ((srow & 7) << 3))] = f2bf(acc[m][n2][r] + bb);
      }
    }
  }
  __syncthreads();

  // ---- linear copy LDS (32 KB) -> att slot rows [s0, s0+64) ----
  {
    f32x4* dst = (f32x4*)(qkOut + (size_t)n * (SS * SS) + (size_t)s0 * 128);
    const f32x4* s4 = (const f32x4*)sE;
    #pragma unroll
    for (int it = 0; it < 4; it++) dst[it * 512 + tid] = s4[it * 512 + tid];
  }
}

// ============================================================================
// K2 attn: per node. Load Q|K (64 KB, already swizzle-laid-out) -> LDS,
// S = Q K^T via MFMA, tanh, store att (overwrites slot), colmean -> c[n].
// ============================================================================
#define AT_LDS (65536 + 4096)
__global__ __launch_bounds__(512, 2)
void attn(float* __restrict__ attIO, float* __restrict__ cOut)
{
  extern __shared__ char lds[];
  unsigned short* sQK = (unsigned short*)lds;          // [128][256] bf16
  float* scr = (float*)(lds + 65536);                  // [8][128]

  const int n    = blockIdx.x;
  const int tid  = threadIdx.x;
  const int wid  = tid >> 6;
  const int lane = tid & 63;
  const int lx   = lane & 15;
  const int g    = lane >> 4;
  const int sw   = (lx & 7) << 3;

  float* slot = attIO + (size_t)n * (SS * SS);

  // ---- load 64 KB slot -> LDS (linear) ----
  {
    const u32x4* src = (const u32x4*)slot;
    u32x4* dst = (u32x4*)sQK;
    #pragma unroll
    for (int it = 0; it < 8; it++) dst[it * 512 + tid] = src[it * 512 + tid];
  }
  __syncthreads();

  // ---- S = Q K^T ----
  bf16x8 qf[4];
  #pragma unroll
  for (int ks = 0; ks < 4; ks++)
    qf[ks] = __builtin_bit_cast(bf16x8,
      *(const u32x4*)(sQK + (wid * 16 + lx) * 256 + ((ks * 32 + g * 8) ^ sw)));

  f32x4 accS[8];
  #pragma unroll
  for (int nt = 0; nt < 8; nt++) accS[nt] = f32x4{0,0,0,0};
  #pragma unroll
  for (int nt = 0; nt < 8; nt++) {
    const int tr = nt * 16 + lx;
    #pragma unroll
    for (int ks = 0; ks < 4; ks++) {
      u32x4 t = *(const u32x4*)(sQK + tr * 256 + 128 + ((ks * 32 + g * 8) ^ sw));
      accS[nt] = __builtin_amdgcn_mfma_f32_16x16x32_bf16(
                   qf[ks], __builtin_bit_cast(bf16x8, t), accS[nt], 0, 0, 0);
    }
  }

  // ---- tanh, att store, colsum partials ----
  {
    const int srow0 = wid * 16 + g * 4;
    float colp[8];
    #pragma unroll
    for (int nt = 0; nt < 8; nt++) {
      float p = 0.f;
      #pragma unroll
      for (int r = 0; r < 4; r++) {
        float x  = accS[nt][r] * 0.0625f;        // 1/sqrt(256)
        float ax = fabsf(x);
        float ex = __expf(ax * 2.0f);
        float th = __builtin_copysignf(__fdividef(ex - 1.0f, ex + 1.0f), x);
        p += th;
        slot[(size_t)(srow0 + r) * SS + nt * 16 + lx] = th;
      }
      p += __shfl_xor(p, 16, 64);
      p += __shfl_xor(p, 32, 64);
      colp[nt] = p;
    }
    if (lane < 16) {
      #pragma unroll
      for (int nt = 0; nt < 8; nt++) scr[wid * 128 + nt * 16 + lane] = colp[nt];
    }
  }
  __syncthreads();

  if (tid < 128) {
    float s = 0.f;
    #pragma unroll
    for (int w = 0; w < 8; w++) s += scr[w * 128 + tid];
    cOut[(size_t)n * 128 + tid] = s * (1.0f / 128.0f);
  }
}

// ============================================================================
// K3 z-path: z[n] = ((c@emb[n]) @ Wv + (sum c)*bv) @ Wo + bo
// ============================================================================
__global__ __launch_bounds__(256)
void zker(const float* __restrict__ emb, const float* __restrict__ cIn,
          const float* __restrict__ Wv, const float* __restrict__ bv,
          const float* __restrict__ Wo, const float* __restrict__ bo,
          float* __restrict__ zOut)
{
  __shared__ float cS[128], ceS[256], mS[128], scr2[256], csS[2];
  const int n = blockIdx.x, tid = threadIdx.x;

  if (tid < 128) {
    float c = cIn[(size_t)n * 128 + tid];
    cS[tid] = c;
    float r = c;
    #pragma unroll
    for (int off = 32; off >= 1; off >>= 1) r += __shfl_down(r, off, 64);
    if ((tid & 63) == 0) csS[tid >> 6] = r;
  }
  __syncthreads();

  // ce[e] = sum_t c[t] * emb[n,t,e]   (coalesced row reads)
  {
    const float* e = emb + (size_t)n * (SS * EMBD) + tid;
    float acc = 0.f;
    #pragma unroll 8
    for (int t = 0; t < 128; t++) acc += cS[t] * e[(size_t)t * EMBD];
    ceS[tid] = acc;
  }
  __syncthreads();

  // m[l] = ce @ Wv + csum*bv   (2-way e-split)
  {
    const int l = tid & 127, h = tid >> 7;
    float a = 0.f;
    #pragma unroll 8
    for (int i = 0; i < 128; i++)
      a += ceS[h * 128 + i] * Wv[(size_t)(h * 128 + i) * LL + l];
    scr2[tid] = a;
  }
  __syncthreads();
  if (tid < 128) {
    float csum = csS[0] + csS[1];
    mS[tid] = scr2[tid] + scr2[128 + tid] + csum * bv[tid];
  }
  __syncthreads();

  // z[j] = m @ Wo + bo   (2-way l-split)
  {
    const int j = tid & 127, h = tid >> 7;
    float a = 0.f;
    #pragma unroll 8
    for (int i = 0; i < 64; i++)
      a += mS[h * 64 + i] * Wo[(size_t)(h * 64 + i) * LL + j];
    scr2[tid] = a;
  }
  __syncthreads();
  if (tid < 128)
    zOut[(size_t)n * LL + tid] = scr2[tid] + scr2[128 + tid] + bo[tid];
}

// ============================================================================
// GCN in z-space (scatter 128-dim), then output GEMM to 2000-dim
// ============================================================================
__global__ void gcn_deg(const int* __restrict__ eidx, float* __restrict__ deg) {
  int e = blockIdx.x * 256 + threadIdx.x;
  if (e < EE) atomicAdd(&deg[eidx[EE + e]], 1.0f);
}

__global__ void gcn_dinv(const float* __restrict__ deg, float* __restrict__ dinv) {
  int i = blockIdx.x * 256 + threadIdx.x;
  if (i < NN) dinv[i] = rsqrtf(deg[i] + 1.0f);      // +1 self loop
}

__global__ void gcn_self(const float* __restrict__ dinv, const float* __restrict__ z,
                         float* __restrict__ agg) {
  size_t gidx = (size_t)blockIdx.x * 256 + threadIdx.x;
  int i = (int)(gidx >> 7);
  float di = dinv[i];
  agg[gidx] = di * di * z[gidx];
}

__global__ void gcn_scatter(const int* __restrict__ eidx, const float* __restrict__ dinv,
                            const float* __restrict__ z, float* __restrict__ agg) {
  int w    = (blockIdx.x * blockDim.x + threadIdx.x) >> 6;
  int lane = threadIdx.x & 63;
  int nw   = (gridDim.x * blockDim.x) >> 6;
  for (int e = w; e < EE; e += nw) {
    int s = eidx[e], d = eidx[EE + e];
    float nrm = dinv[s] * dinv[d];
    atomicAdd(&agg[(size_t)d * 128 + lane],      nrm * z[(size_t)s * 128 + lane]);
    atomicAdd(&agg[(size_t)d * 128 + 64 + lane], nrm * z[(size_t)s * 128 + 64 + lane]);
  }
}

__global__ __launch_bounds__(256)
void out_gemm(const float* __restrict__ agg, const float* __restrict__ Wg,
              const float* __restrict__ bg, float* __restrict__ outp) {
  __shared__ float sA[8 * 128];
  const int nb = blockIdx.x * 8;
  const int tid = threadIdx.x;
  {
    const float4* src = (const float4*)(agg + (size_t)nb * 128);
    ((float4*)sA)[tid] = src[tid];
  }
  __syncthreads();
  const int g0 = tid * 8;
  if (g0 < HV) {
    float acc[8][8];
    #pragma unroll
    for (int i = 0; i < 8; i++)
      #pragma unroll
      for (int j = 0; j < 8; j++) acc[i][j] = 0.0f;
    #pragma unroll 2
    for (int l = 0; l < 128; l++) {
      float4 wa = *(const float4*)(Wg + (size_t)l * HV + g0);
      float4 wb = *(const float4*)(Wg + (size_t)l * HV + g0 + 4);
      float w[8] = {wa.x, wa.y, wa.z, wa.w, wb.x, wb.y, wb.z, wb.w};
      #pragma unroll
      for (int i = 0; i < 8; i++) {
        float a = sA[i * 128 + l];
        #pragma unroll
        for (int j = 0; j < 8; j++) acc[i][j] += a * w[j];
      }
    }
    float b[8];
    #pragma unroll
    for (int j = 0; j < 8; j++) b[j] = bg[g0 + j];
    #pragma unroll
    for (int i = 0; i < 8; i++) {
      float4 oa = make_float4(acc[i][0] + b[0], acc[i][1] + b[1], acc[i][2] + b[2], acc[i][3] + b[3]);
      float4 ob = make_float4(acc[i][4] + b[4], acc[i][5] + b[5], acc[i][6] + b[6], acc[i][7] + b[7]);
      *(float4*)(outp + (size_t)(nb + i) * HV + g0)     = oa;
      *(float4*)(outp + (size_t)(nb + i) * HV + g0 + 4) = ob;
    }
  }
}

// ============================================================================
extern "C" void kernel_launch(void* const* d_in, const int* in_sizes, int n_in,
                              void* d_out, int out_size, void* d_ws, size_t ws_size,
                              hipStream_t stream) {
  const float* emb  = (const float*)d_in[0];
  const int*   eidx = (const int*)d_in[1];
  const float* Wq = (const float*)d_in[2];
  const float* bq = (const float*)d_in[3];
  const float* Wk = (const float*)d_in[4];
  const float* bk = (const float*)d_in[5];
  const float* Wv = (const float*)d_in[6];
  const float* bv = (const float*)d_in[7];
  const float* Wo = (const float*)d_in[8];
  const float* bo = (const float*)d_in[9];
  const float* Wg = (const float*)d_in[10];
  const float* bg = (const float*)d_in[11];

  float* out  = (float*)d_out;
  float* attO = out;                                   // [N,S,S] (Q|K staged here first)
  float* zO   = out + (size_t)NN * SS * SS;            // [N,L]
  float* oO   = zO + (size_t)NN * LL;                  // [N,HV]

  float* wsf  = (float*)d_ws;
  float* deg  = wsf;                                   // [N]
  float* dinv = wsf + NN;                              // [N]
  float* agg  = wsf + 2 * NN;                          // [N,128] (4 MB)
  unsigned short* wT = (unsigned short*)(wsf + 2 * NN + (size_t)NN * 128); // 128 KB
  float* cWS  = wsf + 2 * NN + (size_t)NN * 128 + 32768;                   // [N,128] (4 MB)

  (void)in_sizes; (void)n_in; (void)out_size; (void)ws_size;

  hipFuncSetAttribute((const void*)proj,
                      hipFuncAttributeMaxDynamicSharedMemorySize, PJ_LDS);
  hipFuncSetAttribute((const void*)attn,
                      hipFuncAttributeMaxDynamicSharedMemorySize, AT_LDS);

  hipMemsetAsync(deg, 0, NN * sizeof(float), stream);
  gcn_deg <<<EE / 256, 256, 0, stream>>>(eidx, deg);
  gcn_dinv<<<NN / 256, 256, 0, stream>>>(deg, dinv);
  prep_w  <<<(2 * LL * EMBD) / 256, 256, 0, stream>>>(Wq, Wk, wT);

  proj<<<NN * 2, 512, PJ_LDS, stream>>>(emb, wT, bq, bk, attO);
  attn<<<NN, 512, AT_LDS, stream>>>(attO, cWS);
  zker<<<NN, 256, 0, stream>>>(emb, cWS, Wv, bv, Wo, bo, zO);

  gcn_self   <<<NN * 128 / 256, 256, 0, stream>>>(dinv, zO, agg);
  gcn_scatter<<<2048, 256, 0, stream>>>(eidx, dinv, zO, agg);
  out_gemm   <<<NN / 8, 256, 0, stream>>>(agg, Wg, bg, oO);
}

// Round 4
// 850.445 us; speedup vs baseline: 5.2667x; 1.1417x over previous
//
#include <hip/hip_runtime.h>
#include <cstdint>
#include <cstddef>

// Problem constants (fixed by reference)
#define NN   8192
#define SS   128
#define EMBD 256
#define LL   128
#define HV   2000
#define EE   131072

typedef float  f32x4  __attribute__((ext_vector_type(4)));
typedef __bf16 bf16x8 __attribute__((ext_vector_type(8)));
typedef unsigned int   u32x4 __attribute__((ext_vector_type(4)));
typedef unsigned short u16x4 __attribute__((ext_vector_type(4)));

__device__ __forceinline__ unsigned short f2bf(float f) {
  unsigned u; __builtin_memcpy(&u, &f, 4);
  unsigned r = u + 0x7fffu + ((u >> 16) & 1u);   // RNE
  return (unsigned short)(r >> 16);
}

// ============================================================================
// prep: wT[col][e] bf16, col in [0,256): col<128 -> Wq[:,col], else Wk[:,col-128]
// ============================================================================
__global__ void prep_w(const float* __restrict__ Wq, const float* __restrict__ Wk,
                       unsigned short* __restrict__ wT) {
  int idx = blockIdx.x * 256 + threadIdx.x;      // 65536 = 256 cols x 256 e
  int c = idx >> 8, e = idx & 255;
  float v = (c < 128) ? Wq[(size_t)e * LL + c] : Wk[(size_t)e * LL + (c - 128)];
  wT[idx] = f2bf(v);
}

// ============================================================================
// qkatt: fully fused per-node proj + attention. One block = one node, 512 thr.
//  P1: emb[n] f32 -> LDS bf16 [128][256] (row-swizzled)
//  P2: proj in two row-halves; wave w owns output cols [32w, 32w+32).
//      A = emb rows (LDS), B = wT cols (global, L2-hot, reloaded per half/n2).
//      Epilogue overwrites the just-finished emb rows with Q|K bf16 (+bias).
//  P3: S = Q K^T (MFMA), tanh, att -> d_out, colmean -> cOut.
// Barrier discipline:
//  sync A (after P1) ; half0 MFMA ; sync B ; epi0 (rows 0-63) +
//  half1 MFMA (rows 64-127, disjoint) ; sync C ; epi1 ; sync D ; P3.
// ============================================================================
#define QA_LDS (65536 + 4096)
__global__ __launch_bounds__(512, 4)
void qkatt(const float* __restrict__ emb, const unsigned short* __restrict__ wT,
           const float* __restrict__ bq, const float* __restrict__ bk,
           float* __restrict__ attOut, float* __restrict__ cOut)
{
  extern __shared__ char lds[];
  unsigned short* sE = (unsigned short*)lds;           // [128][256] bf16
  float* scr = (float*)(lds + 65536);                  // [8][128]

  const int n    = blockIdx.x;
  const int tid  = threadIdx.x;
  const int wid  = tid >> 6;
  const int lane = tid & 63;
  const int lx   = lane & 15;
  const int g    = lane >> 4;
  const int sw   = (lx & 7) << 3;

  const float* embN = emb + (size_t)n * (SS * EMBD);

  // ---------------- P1: stage emb f32 -> bf16 LDS (swizzled) ----------------
  {
    const f32x4* src = (const f32x4*)embN;             // 8192 f32x4
    #pragma unroll
    for (int it = 0; it < 16; it++) {
      int i = it * 512 + tid;
      f32x4 v = src[i];
      int s = i >> 6, e0 = (i & 63) << 2;
      u16x4 h;
      h[0] = f2bf(v[0]); h[1] = f2bf(v[1]); h[2] = f2bf(v[2]); h[3] = f2bf(v[3]);
      *(u16x4*)(sE + s * 256 + (e0 ^ ((s & 7) << 3))) = h;
    }
  }
  __syncthreads();                                     // sync A

  const int col0 = (wid << 5) + lx;                    // wave's col base (+n2*16)
  float bias[2];
  bias[0] = (col0      < 128) ? bq[col0]      : bk[col0 - 128];
  bias[1] = (col0 + 16 < 128) ? bq[col0 + 16] : bk[col0 + 16 - 128];

  // ---------------- P2: proj, two row-halves --------------------------------
  #pragma unroll 1
  for (int half = 0; half < 2; half++) {
    f32x4 acc[2][4];
    #pragma unroll
    for (int n2 = 0; n2 < 2; n2++)
      #pragma unroll
      for (int m = 0; m < 4; m++) acc[n2][m] = f32x4{0.f, 0.f, 0.f, 0.f};

    #pragma unroll
    for (int n2 = 0; n2 < 2; n2++) {
      u32x4 B[8];
      const unsigned short* wp = wT + (size_t)(col0 + n2 * 16) * 256 + g * 8;
      #pragma unroll
      for (int ks = 0; ks < 8; ks++) B[ks] = *(const u32x4*)(wp + ks * 32);
      #pragma unroll
      for (int m = 0; m < 4; m++) {
        const unsigned short* ap = sE + (half * 64 + m * 16 + lx) * 256;
        #pragma unroll
        for (int ks = 0; ks < 8; ks++) {
          u32x4 A = *(const u32x4*)(ap + ((ks * 32 + g * 8) ^ sw));
          acc[n2][m] = __builtin_amdgcn_mfma_f32_16x16x32_bf16(
                         __builtin_bit_cast(bf16x8, A), __builtin_bit_cast(bf16x8, B[ks]),
                         acc[n2][m], 0, 0, 0);
        }
      }
    }
    __syncthreads();                                   // sync B (half=0) / C (half=1)

    // epilogue: Q|K (+bias) -> bf16 -> rows [64*half, 64*half+64), swizzled
    #pragma unroll
    for (int n2 = 0; n2 < 2; n2++) {
      const int col = col0 + n2 * 16;
      const float bb = bias[n2];
      #pragma unroll
      for (int m = 0; m < 4; m++)
        #pragma unroll
        for (int r = 0; r < 4; r++) {
          const int srow = half * 64 + m * 16 + g * 4 + r;
          sE[srow * 256 + (col ^ ((srow & 7) << 3))] = f2bf(acc[n2][m][r] + bb);
        }
    }
  }
  __syncthreads();                                     // sync D

  // ---------------- P3: S = Q K^T, tanh, att store, colmean -----------------
  bf16x8 qf[4];
  #pragma unroll
  for (int ks = 0; ks < 4; ks++)
    qf[ks] = __builtin_bit_cast(bf16x8,
      *(const u32x4*)(sE + (wid * 16 + lx) * 256 + ((ks * 32 + g * 8) ^ sw)));

  f32x4 accS[8];
  #pragma unroll
  for (int nt = 0; nt < 8; nt++) accS[nt] = f32x4{0.f, 0.f, 0.f, 0.f};
  #pragma unroll
  for (int nt = 0; nt < 8; nt++) {
    const int tr = nt * 16 + lx;
    #pragma unroll
    for (int ks = 0; ks < 4; ks++) {
      u32x4 t = *(const u32x4*)(sE + tr * 256 + 128 + ((ks * 32 + g * 8) ^ sw));
      accS[nt] = __builtin_amdgcn_mfma_f32_16x16x32_bf16(
                   qf[ks], __builtin_bit_cast(bf16x8, t), accS[nt], 0, 0, 0);
    }
  }

  {
    float* slot = attOut + (size_t)n * (SS * SS);
    const int srow0 = wid * 16 + g * 4;
    float colp[8];
    #pragma unroll
    for (int nt = 0; nt < 8; nt++) {
      float p = 0.f;
      #pragma unroll
      for (int r = 0; r < 4; r++) {
        float x  = accS[nt][r] * 0.0625f;              // 1/sqrt(256)
        float ax = fabsf(x);
        float ex = __expf(ax * 2.0f);
        float th = __builtin_copysignf(__fdividef(ex - 1.0f, ex + 1.0f), x);
        p += th;
        slot[(size_t)(srow0 + r) * SS + nt * 16 + lx] = th;
      }
      p += __shfl_xor(p, 16, 64);
      p += __shfl_xor(p, 32, 64);                      // sum over strip's 16 rows
      colp[nt] = p;
    }
    if (lane < 16) {
      #pragma unroll
      for (int nt = 0; nt < 8; nt++) scr[wid * 128 + nt * 16 + lane] = colp[nt];
    }
  }
  __syncthreads();

  if (tid < 128) {
    float s = 0.f;
    #pragma unroll
    for (int w = 0; w < 8; w++) s += scr[w * 128 + tid];
    cOut[(size_t)n * 128 + tid] = s * (1.0f / 128.0f);
  }
}

// ============================================================================
// K3 z-path: z[n] = ((c@emb[n]) @ Wv + (sum c)*bv) @ Wo + bo
// ============================================================================
__global__ __launch_bounds__(256)
void zker(const float* __restrict__ emb, const float* __restrict__ cIn,
          const float* __restrict__ Wv, const float* __restrict__ bv,
          const float* __restrict__ Wo, const float* __restrict__ bo,
          float* __restrict__ zOut)
{
  __shared__ float cS[128], ceS[256], mS[128], scr2[256], csS[2], scrE[1024];
  const int n = blockIdx.x, tid = threadIdx.x;

  if (tid < 128) {
    float c = cIn[(size_t)n * 128 + tid];
    cS[tid] = c;
    float r = c;
    #pragma unroll
    for (int off = 32; off >= 1; off >>= 1) r += __shfl_down(r, off, 64);
    if ((tid & 63) == 0) csS[tid >> 6] = r;
  }
  __syncthreads();

  // ce[e] = sum_t c[t] * emb[n,t,e]  — f32x4 loads, 4 t-rows in flight
  {
    const int h = tid >> 6, lane = tid & 63;
    const f32x4* e4 = (const f32x4*)(emb + (size_t)n * (SS * EMBD));
    f32x4 acc = f32x4{0.f, 0.f, 0.f, 0.f};
    #pragma unroll 8
    for (int t = h; t < 128; t += 4)
      acc += cS[t] * e4[(size_t)t * 64 + lane];
    *(f32x4*)(scrE + h * 256 + lane * 4) = acc;
  }
  __syncthreads();
  if (tid < 256)
    ceS[tid] = scrE[tid] + scrE[256 + tid] + scrE[512 + tid] + scrE[768 + tid];
  __syncthreads();

  // m[l] = ce @ Wv + csum*bv   (2-way e-split)
  {
    const int l = tid & 127, h = tid >> 7;
    float a = 0.f;
    #pragma unroll 8
    for (int i = 0; i < 128; i++)
      a += ceS[h * 128 + i] * Wv[(size_t)(h * 128 + i) * LL + l];
    scr2[tid] = a;
  }
  __syncthreads();
  if (tid < 128) {
    float csum = csS[0] + csS[1];
    mS[tid] = scr2[tid] + scr2[128 + tid] + csum * bv[tid];
  }
  __syncthreads();

  // z[j] = m @ Wo + bo   (2-way l-split)
  {
    const int j = tid & 127, h = tid >> 7;
    float a = 0.f;
    #pragma unroll 8
    for (int i = 0; i < 64; i++)
      a += mS[h * 64 + i] * Wo[(size_t)(h * 64 + i) * LL + j];
    scr2[tid] = a;
  }
  __syncthreads();
  if (tid < 128)
    zOut[(size_t)n * LL + tid] = scr2[tid] + scr2[128 + tid] + bo[tid];
}

// ============================================================================
// GCN in z-space (scatter 128-dim), then output GEMM to 2000-dim
// ============================================================================
__global__ void gcn_deg(const int* __restrict__ eidx, float* __restrict__ deg) {
  int e = blockIdx.x * 256 + threadIdx.x;
  if (e < EE) atomicAdd(&deg[eidx[EE + e]], 1.0f);
}

__global__ void gcn_dinv(const float* __restrict__ deg, float* __restrict__ dinv) {
  int i = blockIdx.x * 256 + threadIdx.x;
  if (i < NN) dinv[i] = rsqrtf(deg[i] + 1.0f);      // +1 self loop
}

__global__ void gcn_self(const float* __restrict__ dinv, const float* __restrict__ z,
                         float* __restrict__ agg) {
  size_t gidx = (size_t)blockIdx.x * 256 + threadIdx.x;
  int i = (int)(gidx >> 7);
  float di = dinv[i];
  agg[gidx] = di * di * z[gidx];
}

__global__ void gcn_scatter(const int* __restrict__ eidx, const float* __restrict__ dinv,
                            const float* __restrict__ z, float* __restrict__ agg) {
  int w    = (blockIdx.x * blockDim.x + threadIdx.x) >> 6;
  int lane = threadIdx.x & 63;
  int nw   = (gridDim.x * blockDim.x) >> 6;
  for (int e = w; e < EE; e += nw) {
    int s = eidx[e], d = eidx[EE + e];
    float nrm = dinv[s] * dinv[d];
    atomicAdd(&agg[(size_t)d * 128 + lane],      nrm * z[(size_t)s * 128 + lane]);
    atomicAdd(&agg[(size_t)d * 128 + 64 + lane], nrm * z[(size_t)s * 128 + 64 + lane]);
  }
}

__global__ __launch_bounds__(256)
void out_gemm(const float* __restrict__ agg, const float* __restrict__ Wg,
              const float* __restrict__ bg, float* __restrict__ outp) {
  __shared__ float sA[8 * 128];
  const int nb = blockIdx.x * 8;
  const int tid = threadIdx.x;
  {
    const float4* src = (const float4*)(agg + (size_t)nb * 128);
    ((float4*)sA)[tid] = src[tid];
  }
  __syncthreads();
  const int g0 = tid * 8;
  if (g0 < HV) {
    float acc[8][8];
    #pragma unroll
    for (int i = 0; i < 8; i++)
      #pragma unroll
      for (int j = 0; j < 8; j++) acc[i][j] = 0.0f;
    #pragma unroll 2
    for (int l = 0; l < 128; l++) {
      float4 wa = *(const float4*)(Wg + (size_t)l * HV + g0);
      float4 wb = *(const float4*)(Wg + (size_t)l * HV + g0 + 4);
      float w[8] = {wa.x, wa.y, wa.z, wa.w, wb.x, wb.y, wb.z, wb.w};
      #pragma unroll
      for (int i = 0; i < 8; i++) {
        float a = sA[i * 128 + l];
        #pragma unroll
        for (int j = 0; j < 8; j++) acc[i][j] += a * w[j];
      }
    }
    float b[8];
    #pragma unroll
    for (int j = 0; j < 8; j++) b[j] = bg[g0 + j];
    #pragma unroll
    for (int i = 0; i < 8; i++) {
      float4 oa = make_float4(acc[i][0] + b[0], acc[i][1] + b[1], acc[i][2] + b[2], acc[i][3] + b[3]);
      float4 ob = make_float4(acc[i][4] + b[4], acc[i][5] + b[5], acc[i][6] + b[6], acc[i][7] + b[7]);
      *(float4*)(outp + (size_t)(nb + i) * HV + g0)     = oa;
      *(float4*)(outp + (size_t)(nb + i) * HV + g0 + 4) = ob;
    }
  }
}

// ============================================================================
extern "C" void kernel_launch(void* const* d_in, const int* in_sizes, int n_in,
                              void* d_out, int out_size, void* d_ws, size_t ws_size,
                              hipStream_t stream) {
  const float* emb  = (const float*)d_in[0];
  const int*   eidx = (const int*)d_in[1];
  const float* Wq = (const float*)d_in[2];
  const float* bq = (const float*)d_in[3];
  const float* Wk = (const float*)d_in[4];
  const float* bk = (const float*)d_in[5];
  const float* Wv = (const float*)d_in[6];
  const float* bv = (const float*)d_in[7];
  const float* Wo = (const float*)d_in[8];
  const float* bo = (const float*)d_in[9];
  const float* Wg = (const float*)d_in[10];
  const float* bg = (const float*)d_in[11];

  float* out  = (float*)d_out;
  float* attO = out;                                   // [N,S,S]
  float* zO   = out + (size_t)NN * SS * SS;            // [N,L]
  float* oO   = zO + (size_t)NN * LL;                  // [N,HV]

  float* wsf  = (float*)d_ws;
  float* deg  = wsf;                                   // [N]
  float* dinv = wsf + NN;                              // [N]
  float* agg  = wsf + 2 * NN;                          // [N,128] (4 MB)
  unsigned short* wT = (unsigned short*)(wsf + 2 * NN + (size_t)NN * 128); // 128 KB
  float* cWS  = wsf + 2 * NN + (size_t)NN * 128 + 32768;                   // [N,128] (4 MB)

  (void)in_sizes; (void)n_in; (void)out_size; (void)ws_size;

  hipFuncSetAttribute((const void*)qkatt,
                      hipFuncAttributeMaxDynamicSharedMemorySize, QA_LDS);

  hipMemsetAsync(deg, 0, NN * sizeof(float), stream);
  gcn_deg <<<EE / 256, 256, 0, stream>>>(eidx, deg);
  gcn_dinv<<<NN / 256, 256, 0, stream>>>(deg, dinv);
  prep_w  <<<(2 * LL * EMBD) / 256, 256, 0, stream>>>(Wq, Wk, wT);

  qkatt<<<NN, 512, QA_LDS, stream>>>(emb, wT, bq, bk, attO, cWS);
  zker <<<NN, 256, 0, stream>>>(emb, cWS, Wv, bv, Wo, bo, zO);

  gcn_self   <<<NN * 128 / 256, 256, 0, stream>>>(dinv, zO, agg);
  gcn_scatter<<<2048, 256, 0, stream>>>(eidx, dinv, zO, agg);
  out_gemm   <<<NN / 8, 256, 0, stream>>>(agg, Wg, bg, oO);
}